// Round 1
// 2522.410 us; speedup vs baseline: 1.5483x; 1.5483x over previous
//
#include <hip/hip_runtime.h>
#include <cfloat>
#include <math.h>

#define B_ 8
#define N_ 100
#define D_ 1024
#define P_ 9900
#define H_ 1024
#define C_ 51
#define TOPK_ 100
#define CAND_ 128   // fp32-selected candidates per batch, re-ranked in fp64

typedef __attribute__((ext_vector_type(8))) short bf16x8;  // 8 bf16 (4 VGPRs)
typedef __attribute__((ext_vector_type(4))) float f32x4;   // MFMA acc

__device__ __forceinline__ ushort f2bf(float x) {           // fp32 -> bf16 RNE
    uint u = __float_as_uint(x);
    return (ushort)((u + 0x7FFFu + ((u >> 16) & 1u)) >> 16);
}
__device__ __forceinline__ float bf2f(ushort h) {
    return __uint_as_float(((uint)h) << 16);
}
// LDS XOR swizzle: row-major [128][64] bf16 (128B rows), bank-uniform b128 reads
__device__ __forceinline__ int swz(int row, int byteInRow) {
    return row * 128 + (byteInRow ^ ((row & 7) << 4));
}

// ---------------------------------------------------------------------------
// W1 (3D x H fp32, row-major) -> W1T hi/lo bf16, transposed [H][3D].
// ---------------------------------------------------------------------------
__global__ __launch_bounds__(256) void w1_split_T(
    const float* __restrict__ W1, ushort* __restrict__ hi, ushort* __restrict__ lo)
{
    __shared__ float tl[32][33];
    const int k0 = blockIdx.x * 32, n0 = blockIdx.y * 32;
    const int tx = threadIdx.x & 31, ty = threadIdx.x >> 5;
#pragma unroll
    for (int r = ty; r < 32; r += 8)
        tl[r][tx] = W1[(long)(k0 + r) * H_ + n0 + tx];
    __syncthreads();
#pragma unroll
    for (int r = ty; r < 32; r += 8) {
        const float x = tl[tx][r];
        const ushort h = f2bf(x);
        hi[(long)(n0 + r) * (3 * D_) + k0 + tx] = h;
        lo[(long)(n0 + r) * (3 * D_) + k0 + tx] = f2bf(x - bf2f(h));
    }
}

// ---------------------------------------------------------------------------
// fp32-accurate GEMM on the matrix pipe via bf16 hi/lo split (3 MFMAs/pair):
// C[z] = A[z] (MxK fp32, lda) @ B (KxN) + bias, with B given pre-split and
// pre-transposed: BThi/BTlo are [N][ldbT] bf16 (row n = column n of B).
// 128x128 tile, BK=64, 4 waves (2x2), mfma_f32_16x16x32_bf16, 4x4 frags/wave.
// ---------------------------------------------------------------------------
__global__ __launch_bounds__(256, 2) void gemm_mfma(
    const float* __restrict__ A, const ushort* __restrict__ BThi,
    const ushort* __restrict__ BTlo, float* __restrict__ C,
    const float* __restrict__ bias,
    int M, int K, int lda, int ldbT, int ldc,
    long strideA, long strideC)
{
    // XCD-chunked bijective swizzle: hardware-consecutive blocks on one XCD
    // walk consecutive logical tiles (bx fastest -> A-tile shared in that L2).
    const long gx = gridDim.x, gy = gridDim.y;
    const long nwg = gx * gy * (long)gridDim.z;
    long hid = blockIdx.x + gx * (blockIdx.y + gy * (long)blockIdx.z);
    const long q = nwg >> 3, rr = nwg & 7;
    const long xcd = hid & 7, tpos = hid >> 3;
    const long lid = (xcd < rr ? xcd * (q + 1) : rr + xcd * q) + tpos;
    const int bx = (int)(lid % gx);
    const long tmp = lid / gx;
    const int by = (int)(tmp % gy);
    const int bz = (int)(tmp / gy);

    A += (long)bz * strideA;
    C += (long)bz * strideC;
    const int m0 = by * 128;
    const int n0 = bx * 128;

    __shared__ ushort AhS[128 * 64], AlS[128 * 64], BhS[128 * 64], BlS[128 * 64];
    char* const Ahp = (char*)AhS;
    char* const Alp = (char*)AlS;
    char* const Bhp = (char*)BhS;
    char* const Blp = (char*)BlS;

    const int tid = threadIdx.x;
    const int l = tid & 63;
    const int w = tid >> 6;
    const int wm = w >> 1, wn = w & 1;
    const int g = l >> 4;      // lane k-group (0..3)
    const int lr = l & 15;     // lane row/col within fragment

    f32x4 acc[4][4];
#pragma unroll
    for (int i = 0; i < 4; ++i)
#pragma unroll
        for (int j = 0; j < 4; ++j) {
            f32x4 z = {0.f, 0.f, 0.f, 0.f};
            acc[i][j] = z;
        }

    for (int k0 = 0; k0 < K; k0 += 64) {
        // ---- global loads: A fp32 (to split), BT bf16 hi/lo (plain copy) ----
        float4 av[8];
#pragma unroll
        for (int i = 0; i < 8; ++i) {
            const int idx = i * 256 + tid;
            int row = m0 + (idx >> 4);
            if (row > M - 1) row = M - 1;      // clamp; results masked on store
            av[i] = *(const float4*)(A + (long)row * lda + k0 + (idx & 15) * 4);
        }
        uint4 bh4[4], bl4[4];
#pragma unroll
        for (int i = 0; i < 4; ++i) {
            const int idx = i * 256 + tid;
            const int r = idx >> 3, u = idx & 7;
            const long off = (long)(n0 + r) * ldbT + k0 + u * 8;
            bh4[i] = *(const uint4*)(BThi + off);
            bl4[i] = *(const uint4*)(BTlo + off);
        }
        __syncthreads();   // previous compute done reading LDS
        // ---- stage to LDS ----
#pragma unroll
        for (int i = 0; i < 4; ++i) {
            const int idx = i * 256 + tid;
            const int r = idx >> 3, u = idx & 7;
            *(uint4*)(Bhp + swz(r, u * 16)) = bh4[i];
            *(uint4*)(Blp + swz(r, u * 16)) = bl4[i];
        }
#pragma unroll
        for (int i = 0; i < 8; ++i) {
            const int idx = i * 256 + tid;
            const int r = idx >> 4, f4 = idx & 15;
            const float4 v = av[i];
            const ushort h0 = f2bf(v.x), h1 = f2bf(v.y);
            const ushort h2 = f2bf(v.z), h3 = f2bf(v.w);
            uint2 ph, pl;
            ph.x = (uint)h0 | ((uint)h1 << 16);
            ph.y = (uint)h2 | ((uint)h3 << 16);
            pl.x = (uint)f2bf(v.x - bf2f(h0)) | ((uint)f2bf(v.y - bf2f(h1)) << 16);
            pl.y = (uint)f2bf(v.z - bf2f(h2)) | ((uint)f2bf(v.w - bf2f(h3)) << 16);
            *(uint2*)(Ahp + swz(r, f4 * 8)) = ph;
            *(uint2*)(Alp + swz(r, f4 * 8)) = pl;
        }
        __syncthreads();
        // ---- MFMA: 2 k-chunks of 32; hi*hi + hi*lo + lo*hi per frag pair ----
#pragma unroll
        for (int kc = 0; kc < 2; ++kc) {
            const int kb = kc * 64 + g * 16;   // byte offset in LDS row
            bf16x8 ah[4], al[4], bh[4], bl[4];
#pragma unroll
            for (int mi = 0; mi < 4; ++mi) {
                const int row = wm * 64 + mi * 16 + lr;
                ah[mi] = *(const bf16x8*)(Ahp + swz(row, kb));
                al[mi] = *(const bf16x8*)(Alp + swz(row, kb));
            }
#pragma unroll
            for (int nj = 0; nj < 4; ++nj) {
                const int col = wn * 64 + nj * 16 + lr;
                bh[nj] = *(const bf16x8*)(Bhp + swz(col, kb));
                bl[nj] = *(const bf16x8*)(Blp + swz(col, kb));
            }
#pragma unroll
            for (int mi = 0; mi < 4; ++mi)
#pragma unroll
                for (int nj = 0; nj < 4; ++nj) {
                    acc[mi][nj] = __builtin_amdgcn_mfma_f32_16x16x32_bf16(
                        ah[mi], bh[nj], acc[mi][nj], 0, 0, 0);
                    acc[mi][nj] = __builtin_amdgcn_mfma_f32_16x16x32_bf16(
                        ah[mi], bl[nj], acc[mi][nj], 0, 0, 0);
                    acc[mi][nj] = __builtin_amdgcn_mfma_f32_16x16x32_bf16(
                        al[mi], bh[nj], acc[mi][nj], 0, 0, 0);
                }
        }
    }

    // epilogue: C/D layout col=lane&15, row=(lane>>4)*4+reg
#pragma unroll
    for (int nj = 0; nj < 4; ++nj) {
        const int col = n0 + wn * 64 + nj * 16 + lr;
        const float bv = bias ? bias[col] : 0.f;
#pragma unroll
        for (int mi = 0; mi < 4; ++mi) {
#pragma unroll
            for (int r = 0; r < 4; ++r) {
                const int row = m0 + wm * 64 + mi * 16 + g * 4 + r;
                if (row < M)
                    C[(long)row * ldc + col] = acc[mi][nj][r] + bv;
            }
        }
    }
}

// ---------------------------------------------------------------------------
// fp32 fused second layer: A = lrelu(subW[si]+objW[oi]+phrW[pi]) built on the
// fly, GEMM with W2 -> logits (output 0). 64 pairs per block.
// ---------------------------------------------------------------------------
__global__ __launch_bounds__(256) void fused_logits(
    const float* __restrict__ subW, const float* __restrict__ objW,
    const float* __restrict__ phrW, const float* __restrict__ W2,
    const float* __restrict__ b2,
    const int* __restrict__ conn, const int* __restrict__ pidx,
    float* __restrict__ outLogits,
    int b0, int h0, int Hc, int initFlag)
{
    const int z = blockIdx.z;
    const int b = b0 + z;
    const int p0 = blockIdx.y * 64;
    const float* __restrict__ phr = phrW + (long)z * P_ * Hc;

    __shared__ float As[32][68];
    __shared__ float Bs[32][68];
    __shared__ int sIdx[64], oIdx[64], pIdx[64];

    const int t = threadIdx.x;
    if (t < 64) {
        const int pp = min(p0 + t, P_ - 1);
        sIdx[t] = conn[(long)b * 2 * P_ + pp];
        oIdx[t] = conn[(long)b * 2 * P_ + P_ + pp];
        pIdx[t] = pidx[(long)b * P_ + pp];
    }
    __syncthreads();

    const int tx = t & 15, ty = t >> 4;
    const int apr = t >> 3;
    const int akq = (t & 7) * 4;
    const int wn = t & 63, wk = t >> 6;

    float acc[4][4];
#pragma unroll
    for (int i = 0; i < 4; ++i)
#pragma unroll
        for (int j = 0; j < 4; ++j) acc[i][j] = 0.f;

    for (int k0 = 0; k0 < Hc; k0 += 32) {
        float breg[8];
#pragma unroll
        for (int i = 0; i < 8; ++i) {
            const int kk = wk + i * 4;
            const int gk = h0 + k0 + kk;
            breg[i] = (wn < C_) ? W2[(long)gk * C_ + wn] : 0.f;
        }
        float4 av[2];
#pragma unroll
        for (int half = 0; half < 2; ++half) {
            const int pr = apr + half * 32;
            const int p = p0 + pr;
            float4 v = make_float4(0.f, 0.f, 0.f, 0.f);
            if (p < P_) {
                const float4 s4 = *(const float4*)(subW + ((long)b * N_ + sIdx[pr]) * H_ + h0 + k0 + akq);
                const float4 o4 = *(const float4*)(objW + ((long)b * N_ + oIdx[pr]) * H_ + h0 + k0 + akq);
                const float4 p4 = *(const float4*)(phr + (long)pIdx[pr] * Hc + k0 + akq);
                v.x = s4.x + o4.x + p4.x;
                v.y = s4.y + o4.y + p4.y;
                v.z = s4.z + o4.z + p4.z;
                v.w = s4.w + o4.w + p4.w;
                v.x = v.x > 0.f ? v.x : 0.01f * v.x;
                v.y = v.y > 0.f ? v.y : 0.01f * v.y;
                v.z = v.z > 0.f ? v.z : 0.01f * v.z;
                v.w = v.w > 0.f ? v.w : 0.01f * v.w;
            }
            av[half] = v;
        }
        __syncthreads();
#pragma unroll
        for (int i = 0; i < 8; ++i) Bs[wk + i * 4][wn] = breg[i];
        As[akq + 0][apr] = av[0].x; As[akq + 1][apr] = av[0].y;
        As[akq + 2][apr] = av[0].z; As[akq + 3][apr] = av[0].w;
        As[akq + 0][apr + 32] = av[1].x; As[akq + 1][apr + 32] = av[1].y;
        As[akq + 2][apr + 32] = av[1].z; As[akq + 3][apr + 32] = av[1].w;
        __syncthreads();

#pragma unroll
        for (int kk = 0; kk < 32; ++kk) {
            float a[4], bv[4];
            *(float4*)a  = *(const float4*)&As[kk][ty * 4];
            *(float4*)bv = *(const float4*)&Bs[kk][tx * 4];
#pragma unroll
            for (int i = 0; i < 4; ++i)
#pragma unroll
                for (int j = 0; j < 4; ++j)
                    acc[i][j] += a[i] * bv[j];
        }
    }

#pragma unroll
    for (int i = 0; i < 4; ++i) {
        const int p = p0 + ty * 4 + i;
        if (p < P_) {
#pragma unroll
            for (int j = 0; j < 4; ++j) {
                const int n = tx * 4 + j;
                if (n < C_) {
                    const long idx = ((long)b * P_ + p) * C_ + n;
                    float v = acc[i][j];
                    v += initFlag ? b2[n] : outLogits[idx];
                    outLogits[idx] = v;
                }
            }
        }
    }
}

// ---------------------------------------------------------------------------
// fp32 softmax per pair: probs (output 1) + overall (for candidate selection)
// ---------------------------------------------------------------------------
__global__ __launch_bounds__(256) void softmax_pred(
    const float* __restrict__ logits, const float* __restrict__ scores,
    const int* __restrict__ conn,
    float* __restrict__ probs, float* __restrict__ overall)
{
    const int wid = blockIdx.x * 4 + (threadIdx.x >> 6);
    if (wid >= B_ * P_) return;
    const int lane = threadIdx.x & 63;
    const int b = wid / P_;
    const int p = wid - b * P_;

    float x = (lane < C_) ? logits[(long)wid * C_ + lane] : -FLT_MAX;
    float m = x;
#pragma unroll
    for (int off = 32; off; off >>= 1) m = fmaxf(m, __shfl_xor(m, off));
    float e = (lane < C_) ? expf(x - m) : 0.f;
    float s = e;
#pragma unroll
    for (int off = 32; off; off >>= 1) s += __shfl_xor(s, off);
    const float pr = e / s;
    if (lane < C_) probs[(long)wid * C_ + lane] = pr;

    float pz = (lane > 0 && lane < C_) ? pr : ((lane == 0) ? 0.f : -FLT_MAX);
#pragma unroll
    for (int off = 32; off; off >>= 1) pz = fmaxf(pz, __shfl_xor(pz, off));
    if (lane == 0) {
        const int si = conn[(long)b * 2 * P_ + p];
        const int oi = conn[(long)b * 2 * P_ + P_ + p];
        overall[wid] = pz * scores[b * N_ + si] * scores[b * N_ + oi];
    }
}

// ---------------------------------------------------------------------------
// Per-batch top-CAND_ candidate indices by fp32 overall (iterative argmax).
// Order/tie-break irrelevant: fp64 stage re-ranks. Only set membership matters.
// ---------------------------------------------------------------------------
__global__ __launch_bounds__(1024) void cand_topk(
    const float* __restrict__ overall, int* __restrict__ cand)
{
    const int b = blockIdx.x;
    __shared__ float vals[P_];
    __shared__ float wv[16];
    __shared__ int wi[16];

    const int t = threadIdx.x;
    for (int i = t; i < P_; i += 1024) vals[i] = overall[(long)b * P_ + i];
    __syncthreads();

    const int lane = t & 63, w = t >> 6;
    for (int it = 0; it < CAND_; ++it) {
        float v = -FLT_MAX;
        int idx = 0x7FFFFFFF;
        for (int i = t; i < P_; i += 1024) {
            const float x = vals[i];
            if (x > v || (x == v && i < idx)) { v = x; idx = i; }
        }
#pragma unroll
        for (int off = 32; off; off >>= 1) {
            const float ov = __shfl_xor(v, off);
            const int   oi = __shfl_xor(idx, off);
            if (ov > v || (ov == v && oi < idx)) { v = ov; idx = oi; }
        }
        if (lane == 0) { wv[w] = v; wi[w] = idx; }
        __syncthreads();
        if (t < 64) {
            v   = (t < 16) ? wv[t] : -FLT_MAX;
            idx = (t < 16) ? wi[t] : 0x7FFFFFFF;
#pragma unroll
            for (int off = 8; off; off >>= 1) {
                const float ov = __shfl_xor(v, off);
                const int   oi = __shfl_xor(idx, off);
                if (ov > v || (ov == v && oi < idx)) { v = ov; idx = oi; }
            }
            if (t == 0) {
                cand[b * CAND_ + it] = idx;
                vals[idx] = -FLT_MAX;
            }
        }
        __syncthreads();
    }
}

// ---------------------------------------------------------------------------
// fp64 recompute of layer 1 for the 1024 candidate pairs:
// h64[m] = lrelu64( gatherfeat(m) @ W1 + b1 ),  M=1024, K=3072, N=1024.
// ---------------------------------------------------------------------------
__global__ __launch_bounds__(256) void feat_gemm64(
    const float* __restrict__ inst, const float* __restrict__ phrase,
    const int* __restrict__ conn, const int* __restrict__ pidx,
    const int* __restrict__ cand,
    const float* __restrict__ W1, const float* __restrict__ b1,
    double* __restrict__ h64)
{
    const int m0 = blockIdx.y * 64;
    const int n0 = blockIdx.x * 64;

    __shared__ double As[16][66];
    __shared__ double Bs[16][66];
    __shared__ int rs[64], ro[64], rp[64], rb[64];

    const int t = threadIdx.x;
    if (t < 64) {
        const int m = m0 + t;
        const int b = m / CAND_;
        const int ci = cand[m];
        rs[t] = conn[(long)b * 2 * P_ + ci];
        ro[t] = conn[(long)b * 2 * P_ + P_ + ci];
        rp[t] = pidx[(long)b * P_ + ci];
        rb[t] = b;
    }
    __syncthreads();

    const int arow = t & 63;
    const int ak4  = (t >> 6) * 4;
    const int bkr  = t >> 4;
    const int bn4  = (t & 15) * 4;
    const int tx = t & 15, ty = t >> 4;

    double acc[4][4];
#pragma unroll
    for (int i = 0; i < 4; ++i)
#pragma unroll
        for (int j = 0; j < 4; ++j) acc[i][j] = 0.0;

    for (int k0 = 0; k0 < 3 * D_; k0 += 16) {
        float4 fa;
        {
            const int b = rb[arow];
            const int k = k0 + ak4;
            const float* src;
            if (k < D_)           src = inst   + ((long)b * N_ + rs[arow]) * D_ + k;
            else if (k < 2 * D_)  src = inst   + ((long)b * N_ + ro[arow]) * D_ + (k - D_);
            else                  src = phrase + ((long)b * P_ + rp[arow]) * D_ + (k - 2 * D_);
            fa = *(const float4*)src;
        }
        const float4 fb = *(const float4*)(W1 + (long)(k0 + bkr) * H_ + n0 + bn4);

        __syncthreads();
        As[ak4 + 0][arow] = (double)fa.x;
        As[ak4 + 1][arow] = (double)fa.y;
        As[ak4 + 2][arow] = (double)fa.z;
        As[ak4 + 3][arow] = (double)fa.w;
        Bs[bkr][bn4 + 0] = (double)fb.x;
        Bs[bkr][bn4 + 1] = (double)fb.y;
        Bs[bkr][bn4 + 2] = (double)fb.z;
        Bs[bkr][bn4 + 3] = (double)fb.w;
        __syncthreads();

#pragma unroll
        for (int kk = 0; kk < 16; ++kk) {
            double a[4], bv[4];
#pragma unroll
            for (int i = 0; i < 4; ++i) a[i]  = As[kk][ty * 4 + i];
#pragma unroll
            for (int j = 0; j < 4; ++j) bv[j] = Bs[kk][tx * 4 + j];
#pragma unroll
            for (int i = 0; i < 4; ++i)
#pragma unroll
                for (int j = 0; j < 4; ++j)
                    acc[i][j] += a[i] * bv[j];
        }
    }

#pragma unroll
    for (int i = 0; i < 4; ++i) {
#pragma unroll
        for (int j = 0; j < 4; ++j) {
            const int m = m0 + ty * 4 + i;
            const int n = n0 + tx * 4 + j;
            double v = acc[i][j] + (double)b1[n];
            v = v > 0.0 ? v : 0.01 * v;
            h64[(long)m * H_ + n] = v;
        }
    }
}

// ---------------------------------------------------------------------------
// fp64 layer 2 for candidates: lg64[c][j] = h64[c] . W2[:,j] + b2[j]
// ---------------------------------------------------------------------------
__global__ __launch_bounds__(64) void logits64_kernel(
    const double* __restrict__ h64, const float* __restrict__ W2,
    const float* __restrict__ b2, double* __restrict__ lg64)
{
    const int c = blockIdx.x;
    const int j = threadIdx.x;
    if (j >= C_) return;
    double s = (double)b2[j];
    const double* __restrict__ hr = h64 + (long)c * H_;
    for (int k = 0; k < H_; ++k)
        s += hr[k] * (double)W2[(long)k * C_ + j];
    lg64[(long)c * C_ + j] = s;
}

// ---------------------------------------------------------------------------
// fp64 softmax + argmax + overall per candidate; rank top-100 per batch.
// ---------------------------------------------------------------------------
__global__ __launch_bounds__(64) void finalize64(
    const double* __restrict__ lg64, const int* __restrict__ cand,
    const int* __restrict__ conn, const float* __restrict__ scores,
    float* __restrict__ outTL, float* __restrict__ outTP,
    float* __restrict__ outTV, float* __restrict__ outTI)
{
    const int b = blockIdx.x;
    const int lane = threadIdx.x;
    __shared__ double ovs[CAND_];
    __shared__ double pps[CAND_];
    __shared__ int pls[CAND_];
    __shared__ int pos[CAND_];

    for (int ci = 0; ci < CAND_; ++ci) {
        const long base = ((long)b * CAND_ + ci) * C_;
        double x = (lane < C_) ? lg64[base + lane] : -1e300;
        double m = x;
#pragma unroll
        for (int off = 32; off; off >>= 1) m = fmax(m, __shfl_xor(m, off));
        double e = (lane < C_) ? exp(x - m) : 0.0;
        double s = e;
#pragma unroll
        for (int off = 32; off; off >>= 1) s += __shfl_xor(s, off);
        const double pr = e / s;
        double pz; int idx;
        if (lane == 0)      { pz = 0.0;    idx = 0; }
        else if (lane < C_) { pz = pr;     idx = lane; }
        else                { pz = -1e300; idx = lane; }
#pragma unroll
        for (int off = 32; off; off >>= 1) {
            const double ov = __shfl_xor(pz, off);
            const int    oi = __shfl_xor(idx, off);
            if (ov > pz || (ov == pz && oi < idx)) { pz = ov; idx = oi; }
        }
        if (lane == 0) {
            const int orig = cand[b * CAND_ + ci];
            const int si = conn[(long)b * 2 * P_ + orig];
            const int oj = conn[(long)b * 2 * P_ + P_ + orig];
            pps[ci] = pz;
            pls[ci] = idx;
            pos[ci] = orig;
            ovs[ci] = pz * (double)scores[b * N_ + si] * (double)scores[b * N_ + oj];
        }
    }
    __syncthreads();

    for (int it = 0; it < TOPK_; ++it) {
        double v0 = ovs[lane],      v1 = ovs[lane + 64];
        int    o0 = pos[lane],      o1 = pos[lane + 64];
        double v; int o, sl;
        if (v1 > v0 || (v1 == v0 && o1 < o0)) { v = v1; o = o1; sl = lane + 64; }
        else                                  { v = v0; o = o0; sl = lane; }
#pragma unroll
        for (int off = 32; off; off >>= 1) {
            const double vv = __shfl_xor(v, off);
            const int    oo = __shfl_xor(o, off);
            const int    ss = __shfl_xor(sl, off);
            if (vv > v || (vv == v && oo < o)) { v = vv; o = oo; sl = ss; }
        }
        if (lane == 0) {
            outTV[b * TOPK_ + it] = (float)v;
            outTI[b * TOPK_ + it] = (float)o;
            outTL[b * TOPK_ + it] = (float)pls[sl];
            outTP[b * TOPK_ + it] = (float)pps[sl];
            ovs[sl] = -1e300;
        }
        __syncthreads();
    }
}

// ---------------------------------------------------------------------------
extern "C" void kernel_launch(void* const* d_in, const int* in_sizes, int n_in,
                              void* d_out, int out_size, void* d_ws, size_t ws_size,
                              hipStream_t stream)
{
    const float* inst   = (const float*)d_in[0];
    const float* phrase = (const float*)d_in[1];
    const float* scores = (const float*)d_in[2];
    const float* W1     = (const float*)d_in[3];
    const float* b1     = (const float*)d_in[4];
    const float* W2     = (const float*)d_in[5];
    const float* b2     = (const float*)d_in[6];
    const int*   conn   = (const int*)d_in[7];
    const int*   pidx   = (const int*)d_in[8];

    float* out = (float*)d_out;
    float* outLogits = out;
    float* outProbs  = out + (long)B_ * P_ * C_;
    float* outTL     = out + 2L * B_ * P_ * C_;
    float* outTP     = outTL + B_ * TOPK_;
    float* outTV     = outTP + B_ * TOPK_;
    float* outTI     = outTV + B_ * TOPK_;

    // workspace layout (doubles first, all sub-blocks 16B-multiples)
    double* h64  = (double*)d_ws;                              // B*CAND*H dbl
    double* lg64 = h64 + (long)B_ * CAND_ * H_;                // B*CAND*C dbl
    float* subW    = (float*)(lg64 + (long)B_ * CAND_ * C_);   // B*N*H
    float* objW    = subW + (long)B_ * N_ * H_;                // B*N*H
    float* overall = objW + (long)B_ * N_ * H_;                // B*P
    int*   cand    = (int*)(overall + (long)B_ * P_);          // B*CAND_
    ushort* W1Thi  = (ushort*)(cand + B_ * CAND_);             // H x 3D bf16
    ushort* W1Tlo  = W1Thi + (long)H_ * 3 * D_;                // H x 3D bf16
    float* phrW    = (float*)(W1Tlo + (long)H_ * 3 * D_);      // nb * P * Hc
    const size_t fixedBytes = (size_t)((char*)phrW - (char*)d_ws);
    const size_t avail = ws_size > fixedBytes ? ws_size - fixedBytes : 0;

    int nb = (int)(avail / ((size_t)P_ * H_ * 4));
    if (nb > B_) nb = B_;
    int Hc = H_;
    if (nb < 1) {
        nb = 1;
        int hc = (int)(avail / ((size_t)P_ * 4));
        hc = (hc / 128) * 128;
        if (hc < 128) hc = 128;
        if (hc > H_) hc = H_;
        Hc = hc;
    }

    // split + transpose W1 into bf16 hi/lo ([H][3D])
    w1_split_T<<<dim3(3 * D_ / 32, H_ / 32), 256, 0, stream>>>(W1, W1Thi, W1Tlo);

    // fp32-accurate MFMA stage: instW (sub uses W1 k-rows [0,D), obj [D,2D))
    gemm_mfma<<<dim3(H_ / 128, 1, B_), 256, 0, stream>>>(
        inst, W1Thi, W1Tlo, subW, nullptr,
        N_, D_, D_, 3 * D_, H_, (long)N_ * D_, (long)N_ * H_);
    gemm_mfma<<<dim3(H_ / 128, 1, B_), 256, 0, stream>>>(
        inst, W1Thi + D_, W1Tlo + D_, objW, nullptr,
        N_, D_, D_, 3 * D_, H_, (long)N_ * D_, (long)N_ * H_);

    // phrase GEMM (k-rows [2D,3D)) + fused logits, chunked to fit ws
    for (int b0 = 0; b0 < B_; b0 += nb) {
        const int zb = (b0 + nb <= B_) ? nb : (B_ - b0);
        for (int h0 = 0; h0 < H_; h0 += Hc) {
            const int hc = (h0 + Hc <= H_) ? Hc : (H_ - h0);
            gemm_mfma<<<dim3(hc / 128, (P_ + 127) / 128, zb), 256, 0, stream>>>(
                phrase + (long)b0 * P_ * D_,
                W1Thi + (long)h0 * (3 * D_) + 2 * D_,
                W1Tlo + (long)h0 * (3 * D_) + 2 * D_,
                phrW, b1 + h0,
                P_, D_, D_, 3 * D_, hc, (long)P_ * D_, (long)P_ * hc);
            fused_logits<<<dim3(1, (P_ + 63) / 64, zb), 256, 0, stream>>>(
                subW, objW, phrW, W2, b2, conn, pidx, outLogits,
                b0, h0, hc, h0 == 0 ? 1 : 0);
        }
    }

    // fp32 softmax -> probs output + overall for candidate selection
    softmax_pred<<<dim3((B_ * P_ + 3) / 4), 256, 0, stream>>>(
        outLogits, scores, conn, outProbs, overall);

    // candidate selection (fp32, superset of true top-100)
    cand_topk<<<dim3(B_), 1024, 0, stream>>>(overall, cand);

    // fp64 recompute of candidates
    feat_gemm64<<<dim3(H_ / 64, (B_ * CAND_) / 64), 256, 0, stream>>>(
        inst, phrase, conn, pidx, cand, W1, b1, h64);
    logits64_kernel<<<dim3(B_ * CAND_), 64, 0, stream>>>(h64, W2, b2, lg64);

    // fp64 softmax + rank -> top-k outputs
    finalize64<<<dim3(B_), 64, 0, stream>>>(
        lg64, cand, conn, scores, outTL, outTP, outTV, outTI);
}